// Round 6
// baseline (791.942 us; speedup 1.0000x reference)
//
#include <hip/hip_runtime.h>
#include <hip/hip_bf16.h>
#include <math.h>

#define NU 50000
#define NFOOD 30000
#define NING 20000
#define NCAT 5000
#define NHAB 10000
#define NNODES 115000
#define NREL 8
#define NEDGE 1500000
#define SCAN_B 256

typedef __attribute__((ext_vector_type(8))) short short8;
typedef __attribute__((ext_vector_type(4))) float f32x4;

static inline size_t alignup(size_t x) { return (x + 255) & ~(size_t)255; }

__device__ inline float bf16_bits_to_f32(unsigned short u) {
  return __uint_as_float(((unsigned)u) << 16);
}
__device__ inline unsigned short f32_to_bf16_bits(float f) {
  unsigned u = __float_as_uint(f);
  unsigned r = u + 0x7fffu + ((u >> 16) & 1u);
  return (unsigned short)(r >> 16);
}

// ================= MFMA bf16 GEMM (projections + layer-2) ==========================
// C[M,N] = op(A)[M,K] @ B_T[N,K] (+bias).  A row-major, lda==K. Bt [N][ldB] bf16.
// Tile 128x128, BK=64, 256 thr = 4 waves. LDS XOR swizzle byte ^= (row&7)<<4.
template <bool A_F32, bool OUT_BF16>
__global__ __launch_bounds__(256) void mfma_gemm(
    const void* __restrict__ Ain, const unsigned short* __restrict__ Bt, int ldB,
    const float* __restrict__ bias, void* __restrict__ Cv, int ldC, int Nstore,
    int M, int N, int K) {
  __shared__ char As[128 * 128];
  __shared__ char Bs[128 * 128];
  const int tid = threadIdx.x;
  const int lane = tid & 63;
  const int wv = tid >> 6;
  const int bm = blockIdx.y * 128;
  const int bn = blockIdx.x * 128;
  f32x4 acc[2][8] = {};

  for (int k0 = 0; k0 < K; k0 += 64) {
    if (A_F32) {
      const float* A = (const float*)Ain;
#pragma unroll
      for (int it = 0; it < 4; ++it) {
        int u = it * 256 + tid;
        int m = u >> 3, c = u & 7;
        int mg = bm + m; if (mg >= M) mg = M - 1;
        const float4* src = (const float4*)(A + (size_t)mg * K + k0 + c * 8);
        float4 lo4 = src[0], hi4 = src[1];
        unsigned q0 = f32_to_bf16_bits(lo4.x) | ((unsigned)f32_to_bf16_bits(lo4.y) << 16);
        unsigned q1 = f32_to_bf16_bits(lo4.z) | ((unsigned)f32_to_bf16_bits(lo4.w) << 16);
        unsigned q2 = f32_to_bf16_bits(hi4.x) | ((unsigned)f32_to_bf16_bits(hi4.y) << 16);
        unsigned q3 = f32_to_bf16_bits(hi4.z) | ((unsigned)f32_to_bf16_bits(hi4.w) << 16);
        int off = m * 128 + ((c * 16) ^ ((m & 7) << 4));
        *(int4*)(As + off) = make_int4(q0, q1, q2, q3);
      }
    } else {
      const unsigned short* A = (const unsigned short*)Ain;
#pragma unroll
      for (int it = 0; it < 4; ++it) {
        int u = it * 256 + tid;
        int m = u >> 3, c = u & 7;
        int mg = bm + m; if (mg >= M) mg = M - 1;
        int4 v = *(const int4*)((const char*)(A + (size_t)mg * K + k0) + c * 16);
        int off = m * 128 + ((c * 16) ^ ((m & 7) << 4));
        *(int4*)(As + off) = v;
      }
    }
#pragma unroll
    for (int it = 0; it < 4; ++it) {
      int u = it * 256 + tid;
      int n = u >> 3, c = u & 7;
      int4 v = *(const int4*)((const char*)(Bt + (size_t)(bn + n) * ldB + k0) + c * 16);
      int off = n * 128 + ((c * 16) ^ ((n & 7) << 4));
      *(int4*)(Bs + off) = v;
    }
    __syncthreads();
#pragma unroll
    for (int kk = 0; kk < 2; ++kk) {
      int kbyte = kk * 64 + ((lane >> 4) << 4);
      short8 af[2];
#pragma unroll
      for (int mi = 0; mi < 2; ++mi) {
        int m = wv * 32 + mi * 16 + (lane & 15);
        af[mi] = *(const short8*)(As + m * 128 + (kbyte ^ ((m & 7) << 4)));
      }
#pragma unroll
      for (int ni = 0; ni < 8; ++ni) {
        int n = ni * 16 + (lane & 15);
        short8 bf = *(const short8*)(Bs + n * 128 + (kbyte ^ ((n & 7) << 4)));
#pragma unroll
        for (int mi = 0; mi < 2; ++mi)
          acc[mi][ni] = __builtin_amdgcn_mfma_f32_16x16x32_bf16(af[mi], bf, acc[mi][ni], 0, 0, 0);
      }
    }
    __syncthreads();
  }
#pragma unroll
  for (int mi = 0; mi < 2; ++mi) {
#pragma unroll
    for (int r = 0; r < 4; ++r) {
      int row = bm + wv * 32 + mi * 16 + ((lane >> 4) << 2) + r;
      if (row < M) {
#pragma unroll
        for (int ni = 0; ni < 8; ++ni) {
          int col = bn + ni * 16 + (lane & 15);
          if (col < Nstore) {
            float v = acc[mi][ni][r] + (bias ? bias[col] : 0.f);
            if (OUT_BF16)
              ((unsigned short*)Cv)[(size_t)row * ldC + col] = f32_to_bf16_bits(v);
            else
              ((float*)Cv)[(size_t)row * ldC + col] = v;
          }
        }
      }
    }
  }
}

// ================= fused layer-1: CSR means + 9 MFMA rounds, all in registers ======
// Block: 512 thr (8 waves), 128 dsts. Wave w owns dst rows w*16..+16 (lane&15 = row,
// lane>>4 = k-quarter). Round t<8: walk CSR (filter rel t), mean in 32 VGPRs -> A-frag;
// t==8: A = x_all[dst] (root). B staged in LDS per round. Epilogue: +b1, relu, bf16.
__global__ __launch_bounds__(512) void l1_fused(
    const int* __restrict__ row_ptr, const unsigned* __restrict__ packed,
    const unsigned short* __restrict__ xall, const unsigned short* __restrict__ W1T,
    const unsigned short* __restrict__ rootT, const float* __restrict__ b1,
    unsigned short* __restrict__ x1) {
  __shared__ char Bs[128 * 256];
  const int tid = threadIdx.x;
  const int lane = tid & 63;
  const int wv = tid >> 6;        // 0..7
  const int q0 = lane >> 4;       // 0..3 (k-quarter)
  const int r16 = lane & 15;      // A row within 16
  const int dst = blockIdx.x * 128 + wv * 16 + r16;
  int beg = 0, end = 0;
  if (dst < NNODES) {
    beg = row_ptr[dst];
    end = (dst == NNODES - 1) ? NEDGE : row_ptr[dst + 1];
  }
  f32x4 acc[8] = {};

  for (int t = 0; t < 9; ++t) {
    __syncthreads();
    const unsigned short* bsrc = (t < 8) ? (W1T + t * 128) : rootT;
    const int ldb = (t < 8) ? 1024 : 128;
#pragma unroll
    for (int it = 0; it < 4; ++it) {
      int idx = it * 512 + tid;       // 2048 chunks of 16B = 32 KB
      int n = idx >> 4, c = idx & 15;
      int4 v = *(const int4*)((const char*)(bsrc + (size_t)n * ldb) + c * 16);
      *(int4*)(Bs + n * 256 + ((c * 16) ^ ((n & 7) << 4))) = v;
    }
    __syncthreads();

    float s[4][8];
#pragma unroll
    for (int kk = 0; kk < 4; ++kk)
#pragma unroll
      for (int j = 0; j < 8; ++j) s[kk][j] = 0.f;
    float wmean = 1.f;
    if (t < 8) {
      int c = 0;
      for (int e = beg; e < end; ++e) {
        unsigned p = packed[e];
        if ((p >> 17) == (unsigned)t) {
          const char* xr = (const char*)xall + (size_t)(p & 0x1FFFFu) * 256 + q0 * 16;
          ++c;
#pragma unroll
          for (int kk = 0; kk < 4; ++kk) {
            short8 v = *(const short8*)(xr + kk * 64);
#pragma unroll
            for (int j = 0; j < 8; ++j)
              s[kk][j] += bf16_bits_to_f32((unsigned short)v[j]);
          }
        }
      }
      wmean = 1.0f / (float)(c > 0 ? c : 1);
    } else {
      int dl = (dst < NNODES) ? dst : 0;
      const char* xr = (const char*)xall + (size_t)dl * 256 + q0 * 16;
#pragma unroll
      for (int kk = 0; kk < 4; ++kk) {
        short8 v = *(const short8*)(xr + kk * 64);
#pragma unroll
        for (int j = 0; j < 8; ++j) s[kk][j] = bf16_bits_to_f32((unsigned short)v[j]);
      }
    }

    short8 af[4];
#pragma unroll
    for (int kk = 0; kk < 4; ++kk)
#pragma unroll
      for (int j = 0; j < 8; ++j)
        af[kk][j] = (short)f32_to_bf16_bits(s[kk][j] * wmean);

#pragma unroll
    for (int ni = 0; ni < 8; ++ni) {
      int n = ni * 16 + r16;
#pragma unroll
      for (int kk = 0; kk < 4; ++kk) {
        int kbyte = kk * 64 + q0 * 16;
        short8 bf = *(const short8*)(Bs + n * 256 + (kbyte ^ ((n & 7) << 4)));
        acc[ni] = __builtin_amdgcn_mfma_f32_16x16x32_bf16(af[kk], bf, acc[ni], 0, 0, 0);
      }
    }
  }

#pragma unroll
  for (int ni = 0; ni < 8; ++ni) {
#pragma unroll
    for (int r = 0; r < 4; ++r) {
      int row = blockIdx.x * 128 + wv * 16 + q0 * 4 + r;
      int col = ni * 16 + r16;
      if (row < NNODES) {
        float v = acc[ni][r] + b1[col];
        x1[(size_t)row * 128 + col] = f32_to_bf16_bits(fmaxf(v, 0.f));
      }
    }
  }
}

// ================= weight repacks ==================================================
__global__ void build_Bt(const float* __restrict__ W, unsigned short* __restrict__ Wt,
                         int K, int N) {
  int idx = blockIdx.x * blockDim.x + threadIdx.x;
  if (idx >= N * K) return;
  int n = idx / K, k = idx - n * K;
  Wt[idx] = f32_to_bf16_bits(W[(size_t)k * N + n]);
}

// W1 [8,128,128] -> W1T [128 f][1024]: W1T[f][t*128+k] = W1[t][k][f]
__global__ void build_W1T(const float* __restrict__ W1, unsigned short* __restrict__ Wt) {
  int idx = blockIdx.x * blockDim.x + threadIdx.x;
  if (idx >= 128 * 1024) return;
  int f = idx >> 10, c = idx & 1023;
  int t = c >> 7, k = c & 127;
  Wt[idx] = f32_to_bf16_bits(W1[((size_t)t * 128 + k) * 128 + f]);
}

// B2pad [128][128] bf16: n<16: W2[n>>1][k][n&1]; 16<=n<18: root2[k][n-16]; else 0
__global__ void build_B2pad(const float* __restrict__ W2, const float* __restrict__ root2,
                            unsigned short* __restrict__ Bt) {
  int idx = blockIdx.x * blockDim.x + threadIdx.x;
  if (idx >= 128 * 128) return;
  int n = idx >> 7, k = idx & 127;
  float v = 0.f;
  if (n < 16) v = W2[((size_t)(n >> 1) * 128 + k) * 2 + (n & 1)];
  else if (n < 18) v = root2[(size_t)k * 2 + (n - 16)];
  Bt[idx] = f32_to_bf16_bits(v);
}

// ================= CSR build =======================================================
__global__ void count_dst(const int* __restrict__ ei, int* __restrict__ cnt_dst) {
  int e = blockIdx.x * blockDim.x + threadIdx.x;
  int stride = gridDim.x * blockDim.x;
  for (; e < NEDGE; e += stride) {
    unsigned d = (unsigned)ei[NEDGE + e]; if (d >= NNODES) d = 0;
    atomicAdd(cnt_dst + d, 1);
  }
}

__global__ void scan_block(const int* __restrict__ in, int* __restrict__ out,
                           int* __restrict__ bsum, int n) {
  __shared__ int s[SCAN_B];
  int i = blockIdx.x * SCAN_B + threadIdx.x;
  int x = (i < n) ? in[i] : 0;
  s[threadIdx.x] = x;
  __syncthreads();
  for (int d = 1; d < SCAN_B; d <<= 1) {
    int v = (threadIdx.x >= d) ? s[threadIdx.x - d] : 0;
    __syncthreads();
    s[threadIdx.x] += v;
    __syncthreads();
  }
  if (i < n) out[i] = s[threadIdx.x] - x;
  if (threadIdx.x == SCAN_B - 1) bsum[blockIdx.x] = s[threadIdx.x];
}

__global__ void scan_top(int* __restrict__ bsum, int* __restrict__ bofs, int nb) {
  __shared__ int s[512];
  int x = (threadIdx.x < nb) ? bsum[threadIdx.x] : 0;
  s[threadIdx.x] = x;
  __syncthreads();
  for (int d = 1; d < 512; d <<= 1) {
    int v = (threadIdx.x >= d) ? s[threadIdx.x - d] : 0;
    __syncthreads();
    s[threadIdx.x] += v;
    __syncthreads();
  }
  if (threadIdx.x < nb) bofs[threadIdx.x] = s[threadIdx.x] - x;
}

__global__ void scan_apply(int* __restrict__ row_ptr, const int* __restrict__ bofs,
                           int* __restrict__ slot, int n) {
  int i = blockIdx.x * blockDim.x + threadIdx.x;
  if (i >= n) return;
  int v = row_ptr[i] + bofs[i / SCAN_B];
  row_ptr[i] = v;
  slot[i] = v;
}

__global__ void scatter_edges(const int* __restrict__ ei, const int* __restrict__ et,
                              int* __restrict__ slot, unsigned* __restrict__ packed) {
  int e = blockIdx.x * blockDim.x + threadIdx.x;
  int stride = gridDim.x * blockDim.x;
  for (; e < NEDGE; e += stride) {
    unsigned s = (unsigned)ei[e];         if (s >= NNODES) s = 0;
    unsigned d = (unsigned)ei[NEDGE + e]; if (d >= NNODES) d = 0;
    unsigned t = (unsigned)et[e];         if (t >= NREL)  t = 0;
    int pos = atomicAdd(slot + d, 1);
    packed[pos] = (t << 17) | s;
  }
}

// ============ layer-2 aggregation + log_softmax (4 lanes per dst) ==================
__global__ void fused_out(const int* __restrict__ row_ptr, const unsigned* __restrict__ packed,
                          const float* __restrict__ h2, const float* __restrict__ b2,
                          float* __restrict__ out) {
  int gt = blockIdx.x * blockDim.x + threadIdx.x;
  int d = gt >> 2;
  int l4 = gt & 3;
  if (d >= NNODES) return;
  int beg = row_ptr[d];
  int end = (d == NNODES - 1) ? NEDGE : row_ptr[d + 1];
  int cnts[8];
#pragma unroll
  for (int q = 0; q < 8; ++q) cnts[q] = 0;
  for (int e = beg; e < end; ++e) {
    unsigned t = packed[e] >> 17;
#pragma unroll
    for (int q = 0; q < 8; ++q) cnts[q] += (t == (unsigned)q);
  }
  float z0 = 0.f, z1 = 0.f;
  for (int e = beg + l4; e < end; e += 4) {
    unsigned p = packed[e];
    unsigned s = p & 0x1FFFFu;
    unsigned t = p >> 17;
    int ct = 1;
#pragma unroll
    for (int q = 0; q < 8; ++q) ct = (t == (unsigned)q) ? cnts[q] : ct;
    float w = 1.0f / (float)(ct > 0 ? ct : 1);
    z0 = fmaf(h2[(size_t)s * 18 + t * 2], w, z0);
    z1 = fmaf(h2[(size_t)s * 18 + t * 2 + 1], w, z1);
  }
  z0 += __shfl_xor(z0, 1, 4); z0 += __shfl_xor(z0, 2, 4);
  z1 += __shfl_xor(z1, 1, 4); z1 += __shfl_xor(z1, 2, 4);
  if (l4 == 0) {
    z0 += h2[(size_t)d * 18 + 16] + b2[0];
    z1 += h2[(size_t)d * 18 + 17] + b2[1];
    float m = fmaxf(z0, z1);
    float l = m + logf(expf(z0 - m) + expf(z1 - m));
    out[(size_t)d * 2 + 0] = z0 - l;
    out[(size_t)d * 2 + 1] = z1 - l;
  }
}

__global__ void fill_sentinel(float* __restrict__ out, int n, float v) {
  int i = blockIdx.x * blockDim.x + threadIdx.x;
  if (i < n) out[i] = v;
}

// ===================================================================================
extern "C" void kernel_launch(void* const* d_in, const int* in_sizes, int n_in,
                              void* d_out, int out_size, void* d_ws, size_t ws_size,
                              hipStream_t stream) {
  const float* x_user = (const float*)d_in[0];
  const float* x_food = (const float*)d_in[1];
  const float* x_ing  = (const float*)d_in[2];
  const float* x_cat  = (const float*)d_in[3];
  const float* x_hab  = (const float*)d_in[4];
  const float* Wu = (const float*)d_in[5];  const float* bu  = (const float*)d_in[6];
  const float* Wf = (const float*)d_in[7];  const float* bfo = (const float*)d_in[8];
  const float* Wi = (const float*)d_in[9];  const float* bi  = (const float*)d_in[10];
  const float* Wc = (const float*)d_in[11]; const float* bc  = (const float*)d_in[12];
  const float* Wh = (const float*)d_in[13]; const float* bh  = (const float*)d_in[14];
  const float* W1 = (const float*)d_in[15]; const float* root1 = (const float*)d_in[16];
  const float* b1 = (const float*)d_in[17];
  const float* W2 = (const float*)d_in[18]; const float* root2 = (const float*)d_in[19];
  const float* b2 = (const float*)d_in[20];
  const int* ei = (const int*)d_in[21];
  const int* et = (const int*)d_in[22];
  (void)in_sizes; (void)n_in;

  dim3 blk(256);
  const int NB1 = (NNODES + SCAN_B - 1) / SCAN_B;   // 450

  // ---- workspace (~75 MB) ----
  char* ws = (char*)d_ws;
  size_t off = 0;
  unsigned short* x_all = (unsigned short*)(ws + off); off += alignup((size_t)NNODES * 128 * 2);
  unsigned short* x1    = (unsigned short*)(ws + off); off += alignup((size_t)NNODES * 128 * 2);
  int* cnt_dst = (int*)(ws + off);       off += alignup((size_t)NNODES * 4);
  int* row_ptr = (int*)(ws + off);       off += alignup((size_t)NNODES * 4);
  int* slot = (int*)(ws + off);          off += alignup((size_t)NNODES * 4);
  unsigned* packed = (unsigned*)(ws + off); off += alignup((size_t)NEDGE * 4);
  int* bsum = (int*)(ws + off);          off += alignup((size_t)512 * 4);
  int* bofs = (int*)(ws + off);          off += alignup((size_t)512 * 4);
  unsigned short* WuT = (unsigned short*)(ws + off); off += alignup((size_t)128 * 256 * 2);
  unsigned short* WfT = (unsigned short*)(ws + off); off += alignup((size_t)128 * 512 * 2);
  unsigned short* WiT = (unsigned short*)(ws + off); off += alignup((size_t)128 * 128 * 2);
  unsigned short* WcT = (unsigned short*)(ws + off); off += alignup((size_t)128 * 64 * 2);
  unsigned short* WhT = (unsigned short*)(ws + off); off += alignup((size_t)128 * 64 * 2);
  unsigned short* rootT = (unsigned short*)(ws + off); off += alignup((size_t)128 * 128 * 2);
  unsigned short* W1T = (unsigned short*)(ws + off); off += alignup((size_t)128 * 1024 * 2);
  unsigned short* B2pad = (unsigned short*)(ws + off); off += alignup((size_t)128 * 128 * 2);
  float* h2 = (float*)(ws + off);        off += alignup((size_t)NNODES * 18 * 4);
  size_t needed = off;

  if (ws_size < needed) {
    fill_sentinel<<<(out_size + 255) / 256, blk, 0, stream>>>((float*)d_out, out_size, -777.0f);
    return;
  }

  hipMemsetAsync(cnt_dst, 0, (size_t)NNODES * 4, stream);

  // ---- weight repacks ----
  build_Bt<<<(128 * 256 + 255) / 256, blk, 0, stream>>>(Wu, WuT, 256, 128);
  build_Bt<<<(128 * 512 + 255) / 256, blk, 0, stream>>>(Wf, WfT, 512, 128);
  build_Bt<<<(128 * 128 + 255) / 256, blk, 0, stream>>>(Wi, WiT, 128, 128);
  build_Bt<<<(128 * 64 + 255) / 256, blk, 0, stream>>>(Wc, WcT, 64, 128);
  build_Bt<<<(128 * 64 + 255) / 256, blk, 0, stream>>>(Wh, WhT, 64, 128);
  build_Bt<<<(128 * 128 + 255) / 256, blk, 0, stream>>>(root1, rootT, 128, 128);
  build_W1T<<<(128 * 1024 + 255) / 256, blk, 0, stream>>>(W1, W1T);
  build_B2pad<<<(128 * 128 + 255) / 256, blk, 0, stream>>>(W2, root2, B2pad);

  // ---- projections -> x_all (bf16) ----
  { dim3 g(1, (NU + 127) / 128);
    mfma_gemm<true, true><<<g, blk, 0, stream>>>(x_user, WuT, 256, bu, (void*)x_all, 128, 128, NU, 128, 256); }
  { dim3 g(1, (NFOOD + 127) / 128);
    mfma_gemm<true, true><<<g, blk, 0, stream>>>(x_food, WfT, 512, bfo, (void*)(x_all + (size_t)NU * 128), 128, 128, NFOOD, 128, 512); }
  { dim3 g(1, (NING + 127) / 128);
    mfma_gemm<true, true><<<g, blk, 0, stream>>>(x_ing, WiT, 128, bi, (void*)(x_all + (size_t)(NU + NFOOD) * 128), 128, 128, NING, 128, 128); }
  { dim3 g(1, (NCAT + 127) / 128);
    mfma_gemm<true, true><<<g, blk, 0, stream>>>(x_cat, WcT, 64, bc, (void*)(x_all + (size_t)(NU + NFOOD + NING) * 128), 128, 128, NCAT, 128, 64); }
  { dim3 g(1, (NHAB + 127) / 128);
    mfma_gemm<true, true><<<g, blk, 0, stream>>>(x_hab, WhT, 64, bh, (void*)(x_all + (size_t)(NU + NFOOD + NING + NCAT) * 128), 128, 128, NHAB, 128, 64); }

  // ---- CSR build ----
  count_dst<<<2048, blk, 0, stream>>>(ei, cnt_dst);
  scan_block<<<NB1, SCAN_B, 0, stream>>>(cnt_dst, row_ptr, bsum, NNODES);
  scan_top<<<1, 512, 0, stream>>>(bsum, bofs, NB1);
  scan_apply<<<NB1, SCAN_B, 0, stream>>>(row_ptr, bofs, slot, NNODES);
  scatter_edges<<<2048, blk, 0, stream>>>(ei, et, slot, packed);

  // ---- fused layer-1: means + 8 rel GEMMs + root + b1 + relu -> x1 (bf16) ----
  l1_fused<<<(NNODES + 127) / 128, dim3(512), 0, stream>>>(
      row_ptr, packed, x_all, W1T, rootT, b1, x1);

  // ---- layer 2: h2 = x1 @ B2pad (store 18 cols) ----
  { dim3 g(1, (NNODES + 127) / 128);
    mfma_gemm<false, false><<<g, blk, 0, stream>>>(x1, B2pad, 128, nullptr, (void*)h2, 18, 18, NNODES, 128, 128); }

  fused_out<<<(NNODES * 4 + 255) / 256, blk, 0, stream>>>(row_ptr, packed, h2, b2, (float*)d_out);
}